// Round 1
// baseline (2334.124 us; speedup 1.0000x reference)
//
#include <hip/hip_runtime.h>
#include <stdint.h>

#define B_ 4
#define S_ 2048
#define D_ 1024
#define H_ 16
#define A_ 64
#define LN_EPS 1e-3f
#define L2E 1.4426950408889634f
#define LDK 40  // padded LDS k-stride (32 + 8)

typedef __bf16 bf16x8 __attribute__((ext_vector_type(8)));
typedef float f32x4 __attribute__((ext_vector_type(4)));

__device__ __forceinline__ f32x4 mfma16(bf16x8 a, bf16x8 b, f32x4 c) {
    return __builtin_amdgcn_mfma_f32_16x16x32_bf16(a, b, c, 0, 0, 0);
}

// ---------------- tiled transpose + f32->bf16 convert ----------------
// in: [g][R][C] f32   out: [g][C][R] bf16
__global__ void k_tr_cvt(const float* __restrict__ in, __bf16* __restrict__ out,
                         int R, int C) {
    __shared__ float tile[32][33];
    size_t gbase = (size_t)blockIdx.z * R * C;
    int r0 = blockIdx.y * 32, c0 = blockIdx.x * 32;
    #pragma unroll
    for (int i = threadIdx.y; i < 32; i += 8)
        tile[i][threadIdx.x] = in[gbase + (size_t)(r0 + i) * C + c0 + threadIdx.x];
    __syncthreads();
    #pragma unroll
    for (int i = threadIdx.y; i < 32; i += 8)
        out[gbase + (size_t)(c0 + i) * R + r0 + threadIdx.x] = (__bf16)tile[threadIdx.x][i];
}

// ---------------- staging helpers (reg-staged global->LDS) ----------------
__device__ __forceinline__ void stage128_bf16(__bf16* dst, const __bf16* src, int ld, int t) {
    #pragma unroll
    for (int i = 0; i < 2; ++i) {
        int id = t + i * 256;
        int row = id >> 2, ch = (id & 3) * 8;
        *(uint4*)(dst + row * LDK + ch) = *(const uint4*)(src + (size_t)row * ld + ch);
    }
}
__device__ __forceinline__ void stage64_bf16(__bf16* dst, const __bf16* src, int ld, int t) {
    int row = t >> 2, ch = (t & 3) * 8;
    *(uint4*)(dst + row * LDK + ch) = *(const uint4*)(src + (size_t)row * ld + ch);
}
__device__ __forceinline__ void stage128_f32(__bf16* dst, const float* src, int ld, int t) {
    #pragma unroll
    for (int i = 0; i < 2; ++i) {
        int id = t + i * 256;
        int row = id >> 2, ch = (id & 3) * 8;
        const float* p = src + (size_t)row * ld + ch;
        float4 f0 = *(const float4*)p;
        float4 f1 = *(const float4*)(p + 4);
        __bf16 v8[8] = {(__bf16)f0.x, (__bf16)f0.y, (__bf16)f0.z, (__bf16)f0.w,
                        (__bf16)f1.x, (__bf16)f1.y, (__bf16)f1.z, (__bf16)f1.w};
        *(uint4*)(dst + row * LDK + ch) = *(const uint4*)v8;
    }
}

template <int NI, int NJ>
__device__ __forceinline__ void mfma_tile(const __bf16* As, const __bf16* Bs,
                                          int wm, int wn, int fr, int fg,
                                          f32x4 (&acc)[NI][NJ]) {
    bf16x8 af[NI], bfv[NJ];
    #pragma unroll
    for (int i = 0; i < NI; ++i)
        af[i] = *(const bf16x8*)(As + (wm + i * 16 + fr) * LDK + fg * 8);
    #pragma unroll
    for (int j = 0; j < NJ; ++j)
        bfv[j] = *(const bf16x8*)(Bs + (wn + j * 16 + fr) * LDK + fg * 8);
    #pragma unroll
    for (int i = 0; i < NI; ++i)
        #pragma unroll
        for (int j = 0; j < NJ; ++j)
            acc[i][j] = mfma16(af[i], bfv[j], acc[i][j]);
}

// ---------------- Q/K projection: [8192x1024] f32 @ Wt[1024][1024] bf16 ----------------
__global__ __launch_bounds__(256) void k_proj_gemm(
    const float* __restrict__ Af, const __bf16* __restrict__ Bt,
    const float* __restrict__ bias, float scale, __bf16* __restrict__ out) {
    __shared__ __bf16 As[128 * LDK];
    __shared__ __bf16 Bs[128 * LDK];
    int m0 = blockIdx.y * 128, n0 = blockIdx.x * 128;
    int t = threadIdx.x, lane = t & 63, w = t >> 6;
    int wm = (w >> 1) * 64, wn = (w & 1) * 64;
    int fr = lane & 15, fg = lane >> 4;
    f32x4 acc[4][4] = {};
    for (int k0 = 0; k0 < D_; k0 += 32) {
        __syncthreads();
        stage128_f32(As, Af + (size_t)m0 * D_ + k0, D_, t);
        stage128_bf16(Bs, Bt + (size_t)n0 * D_ + k0, D_, t);
        __syncthreads();
        mfma_tile<4, 4>(As, Bs, wm, wn, fr, fg, acc);
    }
    #pragma unroll
    for (int j = 0; j < 4; ++j) {
        int n = n0 + wn + j * 16 + fr;
        float bv = bias[n];
        #pragma unroll
        for (int i = 0; i < 4; ++i)
            #pragma unroll
            for (int jj = 0; jj < 4; ++jj) {
                int m = m0 + wm + i * 16 + fg * 4 + jj;
                out[(size_t)m * (H_ * A_) + n] = (__bf16)((acc[i][j][jj] + bv) * scale);
            }
    }
}

// ---------------- scores + exp + row-sum: writes unnormalized P (bf16) + 1/l ----------------
__global__ __launch_bounds__(256) void k_scores(
    const __bf16* __restrict__ qp, const __bf16* __restrict__ kp,
    __bf16* __restrict__ P, float* __restrict__ invl, int hbase) {
    __shared__ __bf16 Qs[64 * 72];
    __shared__ __bf16 Ks[64 * 72];
    int qt = blockIdx.x;
    int hl = blockIdx.y;
    int h = hbase + hl;
    int s0 = qt * 64;
    int t = threadIdx.x, lane = t & 63, w = t >> 6;
    int fr = lane & 15, fg = lane >> 4;
    // stage Q tile [64 x 64]
    #pragma unroll
    for (int i = 0; i < 2; ++i) {
        int id = t + i * 256;
        int row = id >> 3, ch = (id & 7) * 8;
        *(uint4*)(Qs + row * 72 + ch) =
            *(const uint4*)(qp + (size_t)(s0 + row) * (H_ * A_) + h * A_ + ch);
    }
    float lsum[4] = {0.f, 0.f, 0.f, 0.f};
    __bf16* Pb = P + (size_t)hl * S_ * S_;
    for (int kt = 0; kt <= qt; ++kt) {
        int t0 = kt * 64;
        __syncthreads();
        #pragma unroll
        for (int i = 0; i < 2; ++i) {
            int id = t + i * 256;
            int row = id >> 3, ch = (id & 7) * 8;
            *(uint4*)(Ks + row * 72 + ch) =
                *(const uint4*)(kp + (size_t)(t0 + row) * (H_ * A_) + h * A_ + ch);
        }
        __syncthreads();
        f32x4 sacc[4] = {};
        #pragma unroll
        for (int st = 0; st < 2; ++st) {
            bf16x8 aq = *(const bf16x8*)(Qs + (w * 16 + fr) * 72 + st * 32 + fg * 8);
            #pragma unroll
            for (int c = 0; c < 4; ++c) {
                bf16x8 bkf = *(const bf16x8*)(Ks + (c * 16 + fr) * 72 + st * 32 + fg * 8);
                sacc[c] = mfma16(aq, bkf, sacc[c]);
            }
        }
        bool diag = (kt == qt);
        #pragma unroll
        for (int c = 0; c < 4; ++c) {
            int tg = t0 + c * 16 + fr;
            #pragma unroll
            for (int jj = 0; jj < 4; ++jj) {
                int sg = s0 + w * 16 + fg * 4 + jj;
                float p = exp2f(sacc[c][jj] * L2E);
                if (diag && tg > sg) p = 0.f;
                lsum[jj] += p;
                Pb[(size_t)sg * S_ + tg] = (__bf16)p;
            }
        }
    }
    // zero-fill one extra 64-tile past the diagonal for even qt (PV uses 128-row tiles)
    if ((qt & 1) == 0) {
        int t0 = (qt + 1) * 64;
        uint4 z = {0, 0, 0, 0};
        #pragma unroll
        for (int i = 0; i < 2; ++i) {
            int id = t + i * 256;
            int row = id >> 3, ch = (id & 7) * 8;
            *(uint4*)(Pb + (size_t)(s0 + row) * S_ + t0 + ch) = z;
        }
    }
    // reduce row-sums across the 16-lane column group
    #pragma unroll
    for (int jj = 0; jj < 4; ++jj) {
        float v = lsum[jj];
        v += __shfl_xor(v, 1);
        v += __shfl_xor(v, 2);
        v += __shfl_xor(v, 4);
        v += __shfl_xor(v, 8);
        if (fr == 0)
            invl[(size_t)hl * S_ + s0 + w * 16 + fg * 4 + jj] = 1.f / v;
    }
}

// ---------------- P @ V (causal GEMM) with 1/l epilogue -> attn bf16 ----------------
__global__ __launch_bounds__(256) void k_pv_gemm(
    const __bf16* __restrict__ P, const __bf16* __restrict__ kvt,
    const float* __restrict__ invl, __bf16* __restrict__ attn) {
    __shared__ __bf16 As[128 * LDK];
    __shared__ __bf16 Bs[128 * LDK];
    int hl = blockIdx.z;
    int qt = blockIdx.y;
    int n0 = blockIdx.x * 128;
    int m0 = qt * 128;
    int klen = (qt + 1) * 128;
    int t = threadIdx.x, lane = t & 63, w = t >> 6;
    int wm = (w >> 1) * 64, wn = (w & 1) * 64;
    int fr = lane & 15, fg = lane >> 4;
    const __bf16* Ab = P + (size_t)hl * S_ * S_ + (size_t)m0 * S_;
    const __bf16* Bb = kvt + (size_t)n0 * S_;
    f32x4 acc[4][4] = {};
    for (int k0 = 0; k0 < klen; k0 += 32) {
        __syncthreads();
        stage128_bf16(As, Ab + k0, S_, t);
        stage128_bf16(Bs, Bb + k0, S_, t);
        __syncthreads();
        mfma_tile<4, 4>(As, Bs, wm, wn, fr, fg, acc);
    }
    float il[4][4];
    #pragma unroll
    for (int i = 0; i < 4; ++i)
        #pragma unroll
        for (int jj = 0; jj < 4; ++jj)
            il[i][jj] = invl[(size_t)hl * S_ + m0 + wm + i * 16 + fg * 4 + jj];
    #pragma unroll
    for (int j = 0; j < 4; ++j) {
        int n = n0 + wn + j * 16 + fr;
        #pragma unroll
        for (int i = 0; i < 4; ++i)
            #pragma unroll
            for (int jj = 0; jj < 4; ++jj) {
                int m = m0 + wm + i * 16 + fg * 4 + jj;
                attn[(size_t)hl * S_ * D_ + (size_t)m * D_ + n] = (__bf16)(acc[i][j][jj] * il[i][jj]);
            }
    }
}

// ---------------- per-head Wo GEMM + bias + relu + sum over heads ----------------
__global__ __launch_bounds__(256) void k_headsum(
    const __bf16* __restrict__ attn, const __bf16* __restrict__ Wot,
    const float* __restrict__ bo, float* __restrict__ asum,
    int hbase, int hcnt) {
    __shared__ __bf16 As[128 * LDK];
    __shared__ __bf16 Bs[64 * LDK];
    int m0 = blockIdx.y * 128;  // s
    int n0 = blockIdx.x * 64;   // e
    int t = threadIdx.x, lane = t & 63, w = t >> 6;
    int wm = (w >> 1) * 64, wn = (w & 1) * 32;
    int fr = lane & 15, fg = lane >> 4;
    f32x4 sum[4][2] = {};
    for (int h = 0; h < hcnt; ++h) {
        const __bf16* Ab = attn + (size_t)h * S_ * D_ + (size_t)m0 * D_;
        const __bf16* Bb = Wot + (size_t)(hbase + h) * D_ * D_ + (size_t)n0 * D_;
        f32x4 acc[4][2] = {};
        for (int k0 = 0; k0 < D_; k0 += 32) {
            __syncthreads();
            stage128_bf16(As, Ab + k0, D_, t);
            stage64_bf16(Bs, Bb + k0, D_, t);
            __syncthreads();
            mfma_tile<4, 2>(As, Bs, wm, wn, fr, fg, acc);
        }
        #pragma unroll
        for (int j = 0; j < 2; ++j) {
            int n = n0 + wn + j * 16 + fr;
            float bv = bo[(size_t)(hbase + h) * D_ + n];
            #pragma unroll
            for (int i = 0; i < 4; ++i)
                #pragma unroll
                for (int jj = 0; jj < 4; ++jj)
                    sum[i][j][jj] += fmaxf(acc[i][j][jj] + bv, 0.f);
        }
    }
    #pragma unroll
    for (int j = 0; j < 2; ++j) {
        int n = n0 + wn + j * 16 + fr;
        #pragma unroll
        for (int i = 0; i < 4; ++i)
            #pragma unroll
            for (int jj = 0; jj < 4; ++jj) {
                int m = m0 + wm + i * 16 + fg * 4 + jj;
                asum[(size_t)m * D_ + n] += sum[i][j][jj];
            }
    }
}

// ---------------- residual + LayerNorm ----------------
__global__ __launch_bounds__(256) void k_ln(
    const float* __restrict__ x1, const float* __restrict__ x2,
    const float* __restrict__ gamma, const float* __restrict__ beta,
    float* __restrict__ out) {
    int row = blockIdx.x;
    size_t base = (size_t)row * D_;
    int c = threadIdx.x * 4;
    float4 a = *(const float4*)(x1 + base + c);
    float4 b = *(const float4*)(x2 + base + c);
    float x[4] = {a.x + b.x, a.y + b.y, a.z + b.z, a.w + b.w};
    float s = x[0] + x[1] + x[2] + x[3];
    float s2 = x[0] * x[0] + x[1] * x[1] + x[2] * x[2] + x[3] * x[3];
    #pragma unroll
    for (int m = 32; m >= 1; m >>= 1) {
        s += __shfl_xor(s, m);
        s2 += __shfl_xor(s2, m);
    }
    __shared__ float r1[4], r2[4];
    int w = threadIdx.x >> 6;
    if ((threadIdx.x & 63) == 0) { r1[w] = s; r2[w] = s2; }
    __syncthreads();
    s = r1[0] + r1[1] + r1[2] + r1[3];
    s2 = r2[0] + r2[1] + r2[2] + r2[3];
    float mean = s * (1.f / D_);
    float var = s2 * (1.f / D_) - mean * mean;
    float rstd = rsqrtf(var + LN_EPS);
    #pragma unroll
    for (int jj = 0; jj < 4; ++jj)
        out[base + c + jj] = gamma[c + jj] * (x[jj] - mean) * rstd + beta[c + jj];
}

// ---------------- host ----------------
extern "C" void kernel_launch(void* const* d_in, const int* in_sizes, int n_in,
                              void* d_out, int out_size, void* d_ws, size_t ws_size,
                              hipStream_t stream) {
    (void)in_sizes; (void)n_in; (void)out_size;
    const float* qin   = (const float*)d_in[0];
    const float* kvin  = (const float*)d_in[1];
    const float* Wq    = (const float*)d_in[2];
    const float* bq    = (const float*)d_in[3];
    const float* Wk    = (const float*)d_in[4];
    const float* bk    = (const float*)d_in[5];
    const float* Wo    = (const float*)d_in[6];
    const float* bo    = (const float*)d_in[7];
    const float* gamma = (const float*)d_in[8];
    const float* beta  = (const float*)d_in[9];
    float* out = (float*)d_out;
    char* ws = (char*)d_ws;

    size_t off = 0;
    auto alloc = [&](size_t bytes) {
        size_t o = off;
        off += (bytes + 255) & ~(size_t)255;
        return o;
    };
    size_t o_wqt = alloc((size_t)H_ * A_ * D_ * 2);
    size_t o_wkt = alloc((size_t)H_ * A_ * D_ * 2);
    size_t o_wot = alloc((size_t)H_ * D_ * D_ * 2);
    size_t o_kvt = alloc((size_t)B_ * D_ * S_ * 2);
    size_t o_qp  = alloc((size_t)B_ * S_ * H_ * A_ * 2);
    size_t o_kp  = alloc((size_t)B_ * S_ * H_ * A_ * 2);
    size_t o_as  = alloc((size_t)B_ * S_ * D_ * 4);
    size_t fixed = off;
    int HG = 1;
    for (int hg = 16; hg >= 1; hg >>= 1) {
        size_t var = (size_t)hg * S_ * S_ * 2 + (size_t)hg * S_ * D_ * 2 + (size_t)hg * S_ * 4 + 1024;
        if (fixed + var <= ws_size) { HG = hg; break; }
    }
    size_t o_P   = alloc((size_t)HG * S_ * S_ * 2);
    size_t o_att = alloc((size_t)HG * S_ * D_ * 2);
    size_t o_il  = alloc((size_t)HG * S_ * 4);

    __bf16* wqt = (__bf16*)(ws + o_wqt);
    __bf16* wkt = (__bf16*)(ws + o_wkt);
    __bf16* wot = (__bf16*)(ws + o_wot);
    __bf16* kvt = (__bf16*)(ws + o_kvt);
    __bf16* qp  = (__bf16*)(ws + o_qp);
    __bf16* kp  = (__bf16*)(ws + o_kp);
    float*  asum = (float*)(ws + o_as);
    __bf16* Pp  = (__bf16*)(ws + o_P);
    __bf16* att = (__bf16*)(ws + o_att);
    float*  il  = (float*)(ws + o_il);

    // transposed bf16 copies: Wq_t/Wk_t [h][a][d], Wo_t [h][e][d], kv_t [b][d][t]
    k_tr_cvt<<<dim3(A_ / 32, D_ / 32, H_), dim3(32, 8), 0, stream>>>(Wq, wqt, D_, A_);
    k_tr_cvt<<<dim3(A_ / 32, D_ / 32, H_), dim3(32, 8), 0, stream>>>(Wk, wkt, D_, A_);
    k_tr_cvt<<<dim3(D_ / 32, D_ / 32, H_), dim3(32, 8), 0, stream>>>(Wo, wot, D_, D_);
    k_tr_cvt<<<dim3(D_ / 32, S_ / 32, B_), dim3(32, 8), 0, stream>>>(kvin, kvt, S_, D_);
    // projections (q pre-scaled by 1/sqrt(A))
    k_proj_gemm<<<dim3(8, 64), 256, 0, stream>>>(qin, wqt, bq, 0.125f, qp);
    k_proj_gemm<<<dim3(8, 64), 256, 0, stream>>>(kvin, wkt, bk, 1.0f, kp);
    hipMemsetAsync(asum, 0, (size_t)B_ * S_ * D_ * 4, stream);

    for (int b = 0; b < B_; ++b) {
        const __bf16* qpb = qp + (size_t)b * S_ * (H_ * A_);
        const __bf16* kpb = kp + (size_t)b * S_ * (H_ * A_);
        const __bf16* kvtb = kvt + (size_t)b * D_ * S_;
        float* asb = asum + (size_t)b * S_ * D_;
        for (int hbase = 0; hbase < H_; hbase += HG) {
            k_scores<<<dim3(32, HG), 256, 0, stream>>>(qpb, kpb, Pp, il, hbase);
            k_pv_gemm<<<dim3(D_ / 128, S_ / 128, HG), 256, 0, stream>>>(Pp, kvtb, il, att);
            k_headsum<<<dim3(D_ / 64, S_ / 128), 256, 0, stream>>>(att, wot, bo, asb, hbase, HG);
        }
    }
    k_ln<<<B_ * S_, 256, 0, stream>>>(qin, asum, gamma, beta, out);
}

// Round 2
// 2191.717 us; speedup vs baseline: 1.0650x; 1.0650x over previous
//
#include <hip/hip_runtime.h>
#include <stdint.h>

#define B_ 4
#define S_ 2048
#define D_ 1024
#define H_ 16
#define A_ 64
#define LN_EPS 1e-3f
#define L2E 1.4426950408889634f

typedef __bf16 bf16x8 __attribute__((ext_vector_type(8)));
typedef float f32x4 __attribute__((ext_vector_type(4)));

__device__ __forceinline__ f32x4 mfma16(bf16x8 a, bf16x8 b, f32x4 c) {
    return __builtin_amdgcn_mfma_f32_16x16x32_bf16(a, b, c, 0, 0, 0);
}

// async global->LDS, 16B per lane (wave-uniform LDS base + lane*16)
__device__ __forceinline__ void glds16(const void* g, void* l) {
    __builtin_amdgcn_global_load_lds(
        (const __attribute__((address_space(1))) void*)g,
        (__attribute__((address_space(3))) void*)l, 16, 0, 0);
}

// stage a [128 rows][32 k] bf16 tile: 8 chunks of 16 rows (1KB each), 2 per wave
__device__ __forceinline__ void glds_tile128(const __bf16* __restrict__ src, size_t ld,
                                             __bf16* lds, int w, int lane) {
    int r = lane >> 2;
    int c = (lane & 3) * 8;
    #pragma unroll
    for (int i = 0; i < 2; ++i) {
        int r0 = (w + i * 4) * 16;
        glds16(src + (size_t)(r0 + r) * ld + c, lds + r0 * 32);
    }
}

// fragment loads from linear [128][32] LDS + MFMA block
template <int NI, int NJ>
__device__ __forceinline__ void mfma_tileL(const __bf16* As, const __bf16* Bs,
                                           int wm, int wn, int fr, int fg,
                                           f32x4 (&acc)[NI][NJ]) {
    bf16x8 af[NI], bv[NJ];
    #pragma unroll
    for (int i = 0; i < NI; ++i)
        af[i] = *(const bf16x8*)(As + (wm + i * 16 + fr) * 32 + fg * 8);
    #pragma unroll
    for (int j = 0; j < NJ; ++j)
        bv[j] = *(const bf16x8*)(Bs + (wn + j * 16 + fr) * 32 + fg * 8);
    #pragma unroll
    for (int i = 0; i < NI; ++i)
        #pragma unroll
        for (int j = 0; j < NJ; ++j)
            acc[i][j] = mfma16(af[i], bv[j], acc[i][j]);
}

// ---------------- tiled transpose + f32->bf16 convert ----------------
__global__ void k_tr_cvt(const float* __restrict__ in, __bf16* __restrict__ out,
                         int R, int C) {
    __shared__ float tile[32][33];
    size_t gbase = (size_t)blockIdx.z * R * C;
    int r0 = blockIdx.y * 32, c0 = blockIdx.x * 32;
    #pragma unroll
    for (int i = threadIdx.y; i < 32; i += 8)
        tile[i][threadIdx.x] = in[gbase + (size_t)(r0 + i) * C + c0 + threadIdx.x];
    __syncthreads();
    #pragma unroll
    for (int i = threadIdx.y; i < 32; i += 8)
        out[gbase + (size_t)(c0 + i) * R + r0 + threadIdx.x] = (__bf16)tile[threadIdx.x][i];
}

// ---------------- elementwise f32 -> bf16 ----------------
__global__ void k_cvt(const float* __restrict__ in, __bf16* __restrict__ out, int n8) {
    int i = blockIdx.x * blockDim.x + threadIdx.x;
    if (i >= n8) return;
    const float4* p = (const float4*)(in + (size_t)i * 8);
    float4 f0 = p[0], f1 = p[1];
    __bf16 v[8] = {(__bf16)f0.x, (__bf16)f0.y, (__bf16)f0.z, (__bf16)f0.w,
                   (__bf16)f1.x, (__bf16)f1.y, (__bf16)f1.z, (__bf16)f1.w};
    *(uint4*)(out + (size_t)i * 8) = *(const uint4*)v;
}

// ---------------- Q/K projection: [B*S x D] bf16 @ Wt[D x D] bf16 ----------------
__global__ __launch_bounds__(256) void k_proj_gemm(
    const __bf16* __restrict__ Ab, const __bf16* __restrict__ Bt,
    const float* __restrict__ bias, float scale, __bf16* __restrict__ out) {
    __shared__ __bf16 As[128 * 32];
    __shared__ __bf16 Bs[128 * 32];
    int m0 = blockIdx.y * 128, n0 = blockIdx.x * 128;
    int t = threadIdx.x, lane = t & 63, w = t >> 6;
    int wm = (w >> 1) * 64, wn = (w & 1) * 64;
    int fr = lane & 15, fg = lane >> 4;
    f32x4 acc[4][4] = {};
    for (int k0 = 0; k0 < D_; k0 += 32) {
        __syncthreads();
        glds_tile128(Ab + (size_t)m0 * D_ + k0, D_, As, w, lane);
        glds_tile128(Bt + (size_t)n0 * D_ + k0, D_, Bs, w, lane);
        __syncthreads();
        mfma_tileL<4, 4>(As, Bs, wm, wn, fr, fg, acc);
    }
    #pragma unroll
    for (int j = 0; j < 4; ++j) {
        int n = n0 + wn + j * 16 + fr;
        float bv = bias[n];
        #pragma unroll
        for (int i = 0; i < 4; ++i)
            #pragma unroll
            for (int jj = 0; jj < 4; ++jj) {
                int m = m0 + wm + i * 16 + fg * 4 + jj;
                out[(size_t)m * (H_ * A_) + n] = (__bf16)((acc[i][j][jj] + bv) * scale);
            }
    }
}

// ---------------- scores + exp + row-sum: unnormalized P (bf16) + 1/l ----------------
__global__ __launch_bounds__(256) void k_scores(
    const __bf16* __restrict__ qp, const __bf16* __restrict__ kp,
    __bf16* __restrict__ P, float* __restrict__ invl, int hbase, int bbase) {
    __shared__ __bf16 Qs[64 * 72];
    __shared__ __bf16 Ks[64 * 72];
    int qt = blockIdx.x;
    int hl = blockIdx.y;
    int bg = blockIdx.z;
    int h = hbase + hl;
    int b = bbase + bg;
    int s0 = qt * 64;
    int t = threadIdx.x, lane = t & 63, w = t >> 6;
    int fr = lane & 15, fg = lane >> 4;
    const __bf16* qpb = qp + (size_t)b * S_ * (H_ * A_);
    const __bf16* kpb = kp + (size_t)b * S_ * (H_ * A_);
    __bf16* Pb = P + (size_t)(bg * gridDim.y + hl) * S_ * S_;
    float* ilb = invl + (size_t)(bg * gridDim.y + hl) * S_;
    #pragma unroll
    for (int i = 0; i < 2; ++i) {
        int id = t + i * 256;
        int row = id >> 3, ch = (id & 7) * 8;
        *(uint4*)(Qs + row * 72 + ch) =
            *(const uint4*)(qpb + (size_t)(s0 + row) * (H_ * A_) + h * A_ + ch);
    }
    float lsum[4] = {0.f, 0.f, 0.f, 0.f};
    for (int kt = 0; kt <= qt; ++kt) {
        int t0 = kt * 64;
        __syncthreads();
        #pragma unroll
        for (int i = 0; i < 2; ++i) {
            int id = t + i * 256;
            int row = id >> 3, ch = (id & 7) * 8;
            *(uint4*)(Ks + row * 72 + ch) =
                *(const uint4*)(kpb + (size_t)(t0 + row) * (H_ * A_) + h * A_ + ch);
        }
        __syncthreads();
        f32x4 sacc[4] = {};
        #pragma unroll
        for (int st = 0; st < 2; ++st) {
            bf16x8 aq = *(const bf16x8*)(Qs + (w * 16 + fr) * 72 + st * 32 + fg * 8);
            #pragma unroll
            for (int c = 0; c < 4; ++c) {
                bf16x8 bkf = *(const bf16x8*)(Ks + (c * 16 + fr) * 72 + st * 32 + fg * 8);
                sacc[c] = mfma16(aq, bkf, sacc[c]);
            }
        }
        bool diag = (kt == qt);
        #pragma unroll
        for (int c = 0; c < 4; ++c) {
            int tg = t0 + c * 16 + fr;
            #pragma unroll
            for (int jj = 0; jj < 4; ++jj) {
                int sg = s0 + w * 16 + fg * 4 + jj;
                float p = exp2f(sacc[c][jj] * L2E);
                if (diag && tg > sg) p = 0.f;
                lsum[jj] += p;
                Pb[(size_t)sg * S_ + tg] = (__bf16)p;
            }
        }
    }
    // zero-fill one extra 64-tile past the diagonal for even qt (PV uses 128-row tiles)
    if ((qt & 1) == 0) {
        int t0 = (qt + 1) * 64;
        uint4 z = {0, 0, 0, 0};
        #pragma unroll
        for (int i = 0; i < 2; ++i) {
            int id = t + i * 256;
            int row = id >> 3, ch = (id & 7) * 8;
            *(uint4*)(Pb + (size_t)(s0 + row) * S_ + t0 + ch) = z;
        }
    }
    #pragma unroll
    for (int jj = 0; jj < 4; ++jj) {
        float v = lsum[jj];
        v += __shfl_xor(v, 1);
        v += __shfl_xor(v, 2);
        v += __shfl_xor(v, 4);
        v += __shfl_xor(v, 8);
        if (fr == 0)
            ilb[s0 + w * 16 + fg * 4 + jj] = 1.f / v;
    }
}

// ---------------- P @ V (causal GEMM) with 1/l epilogue -> attn bf16 ----------------
__global__ __launch_bounds__(256) void k_pv_gemm(
    const __bf16* __restrict__ P, const __bf16* __restrict__ kvt,
    const float* __restrict__ invl, __bf16* __restrict__ attn,
    int bbase, int HG) {
    __shared__ __bf16 As[128 * 32];
    __shared__ __bf16 Bs[128 * 32];
    int z = blockIdx.z;
    int bg = z / HG;
    int qt = blockIdx.y;
    int n0 = blockIdx.x * 128;
    int m0 = qt * 128;
    int klen = (qt + 1) * 128;
    int t = threadIdx.x, lane = t & 63, w = t >> 6;
    int wm = (w >> 1) * 64, wn = (w & 1) * 64;
    int fr = lane & 15, fg = lane >> 4;
    const __bf16* Ab = P + (size_t)z * S_ * S_ + (size_t)m0 * S_;
    const __bf16* Bb = kvt + (size_t)(bbase + bg) * D_ * S_ + (size_t)n0 * S_;
    f32x4 acc[4][4] = {};
    for (int k0 = 0; k0 < klen; k0 += 32) {
        __syncthreads();
        glds_tile128(Ab + k0, S_, As, w, lane);
        glds_tile128(Bb + k0, S_, Bs, w, lane);
        __syncthreads();
        mfma_tileL<4, 4>(As, Bs, wm, wn, fr, fg, acc);
    }
    const float* ilb = invl + (size_t)z * S_;
    float il[4][4];
    #pragma unroll
    for (int i = 0; i < 4; ++i)
        #pragma unroll
        for (int jj = 0; jj < 4; ++jj)
            il[i][jj] = ilb[m0 + wm + i * 16 + fg * 4 + jj];
    __bf16* ob = attn + (size_t)z * S_ * D_;
    #pragma unroll
    for (int j = 0; j < 4; ++j) {
        int n = n0 + wn + j * 16 + fr;
        #pragma unroll
        for (int i = 0; i < 4; ++i)
            #pragma unroll
            for (int jj = 0; jj < 4; ++jj) {
                int m = m0 + wm + i * 16 + fg * 4 + jj;
                ob[(size_t)m * D_ + n] = (__bf16)(acc[i][j][jj] * il[i][jj]);
            }
    }
}

// ---------------- per-head Wo GEMM + bias + relu + partial head-sums ----------------
__global__ __launch_bounds__(256) void k_headsum(
    const __bf16* __restrict__ attn, const __bf16* __restrict__ Wot,
    const float* __restrict__ bo, float* __restrict__ asum,
    int hbase, int HG, int NP, int bbase) {
    __shared__ __bf16 As[128 * 32];
    __shared__ __bf16 Bs[128 * 32];
    int HC = HG / NP;
    int z = blockIdx.z;
    int bg = z / NP, p = z % NP;
    int m0 = blockIdx.y * 128;
    int n0 = blockIdx.x * 128;
    int t = threadIdx.x, lane = t & 63, w = t >> 6;
    int wm = (w >> 1) * 64, wn = (w & 1) * 64;
    int fr = lane & 15, fg = lane >> 4;
    f32x4 sum[4][4] = {};
    for (int hc = 0; hc < HC; ++hc) {
        int hl = p * HC + hc;
        const __bf16* Ab = attn + ((size_t)(bg * HG + hl) * S_ + m0) * D_;
        const __bf16* Bb = Wot + ((size_t)(hbase + hl) * D_ + n0) * D_;
        f32x4 acc[4][4] = {};
        for (int k0 = 0; k0 < D_; k0 += 32) {
            __syncthreads();
            glds_tile128(Ab + k0, D_, As, w, lane);
            glds_tile128(Bb + k0, D_, Bs, w, lane);
            __syncthreads();
            mfma_tileL<4, 4>(As, Bs, wm, wn, fr, fg, acc);
        }
        #pragma unroll
        for (int j = 0; j < 4; ++j) {
            int n = n0 + wn + j * 16 + fr;
            float bv = bo[(size_t)(hbase + hl) * D_ + n];
            #pragma unroll
            for (int i = 0; i < 4; ++i)
                #pragma unroll
                for (int jj = 0; jj < 4; ++jj)
                    sum[i][j][jj] += fmaxf(acc[i][j][jj] + bv, 0.f);
        }
    }
    float* dst = asum + (((size_t)(bbase + bg) * NP + p) * S_) * D_;
    #pragma unroll
    for (int j = 0; j < 4; ++j) {
        int n = n0 + wn + j * 16 + fr;
        #pragma unroll
        for (int i = 0; i < 4; ++i)
            #pragma unroll
            for (int jj = 0; jj < 4; ++jj) {
                int m = m0 + wm + i * 16 + fg * 4 + jj;
                dst[(size_t)m * D_ + n] += sum[i][j][jj];
            }
    }
}

// ---------------- residual + partial-sum + LayerNorm ----------------
__global__ __launch_bounds__(256) void k_ln(
    const float* __restrict__ x1, const float* __restrict__ parts,
    const float* __restrict__ gamma, const float* __restrict__ beta,
    float* __restrict__ out, int NP) {
    int row = blockIdx.x;
    int b = row >> 11, s = row & (S_ - 1);
    size_t base = (size_t)row * D_;
    int c = threadIdx.x * 4;
    float4 a = *(const float4*)(x1 + base + c);
    float x[4] = {a.x, a.y, a.z, a.w};
    for (int p = 0; p < NP; ++p) {
        const float4 v = *(const float4*)(parts + (((size_t)b * NP + p) * S_ + s) * D_ + c);
        x[0] += v.x; x[1] += v.y; x[2] += v.z; x[3] += v.w;
    }
    float sm = x[0] + x[1] + x[2] + x[3];
    float s2 = x[0] * x[0] + x[1] * x[1] + x[2] * x[2] + x[3] * x[3];
    #pragma unroll
    for (int m = 32; m >= 1; m >>= 1) {
        sm += __shfl_xor(sm, m);
        s2 += __shfl_xor(s2, m);
    }
    __shared__ float r1[4], r2[4];
    int w = threadIdx.x >> 6;
    if ((threadIdx.x & 63) == 0) { r1[w] = sm; r2[w] = s2; }
    __syncthreads();
    sm = r1[0] + r1[1] + r1[2] + r1[3];
    s2 = r2[0] + r2[1] + r2[2] + r2[3];
    float mean = sm * (1.f / D_);
    float var = s2 * (1.f / D_) - mean * mean;
    float rstd = rsqrtf(var + LN_EPS);
    #pragma unroll
    for (int jj = 0; jj < 4; ++jj)
        out[base + c + jj] = gamma[c + jj] * (x[jj] - mean) * rstd + beta[c + jj];
}

// ---------------- host ----------------
extern "C" void kernel_launch(void* const* d_in, const int* in_sizes, int n_in,
                              void* d_out, int out_size, void* d_ws, size_t ws_size,
                              hipStream_t stream) {
    (void)in_sizes; (void)n_in; (void)out_size;
    const float* qin   = (const float*)d_in[0];
    const float* kvin  = (const float*)d_in[1];
    const float* Wq    = (const float*)d_in[2];
    const float* bq    = (const float*)d_in[3];
    const float* Wk    = (const float*)d_in[4];
    const float* bk    = (const float*)d_in[5];
    const float* Wo    = (const float*)d_in[6];
    const float* bo    = (const float*)d_in[7];
    const float* gamma = (const float*)d_in[8];
    const float* beta  = (const float*)d_in[9];
    float* out = (float*)d_out;
    char* ws = (char*)d_ws;

    size_t off = 0;
    auto alloc = [&](size_t bytes) {
        size_t o = off;
        off += (bytes + 255) & ~(size_t)255;
        return o;
    };
    size_t o_wqt = alloc((size_t)H_ * A_ * D_ * 2);
    size_t o_wkt = alloc((size_t)H_ * A_ * D_ * 2);
    size_t o_wot = alloc((size_t)H_ * D_ * D_ * 2);
    size_t o_kvt = alloc((size_t)B_ * D_ * S_ * 2);
    size_t o_qb  = alloc((size_t)B_ * S_ * D_ * 2);
    size_t o_kvb = alloc((size_t)B_ * S_ * D_ * 2);
    size_t o_qp  = alloc((size_t)B_ * S_ * H_ * A_ * 2);
    size_t o_kp  = alloc((size_t)B_ * S_ * H_ * A_ * 2);
    size_t fixed = off;

    // choose batch-group x head-group (maximize product), then partial count
    int BG = 1, HG = 1, NP = 1;
    bool found = false;
    for (int G = B_ * H_; G >= 1 && !found; G >>= 1) {
        int bg = (G >= B_) ? B_ : G;
        int hg = G / bg;
        if (hg > H_) continue;
        for (int np = (hg >= 4 ? 4 : hg); np >= 1 && !found; np >>= 1) {
            size_t need = fixed
                        + (size_t)B_ * np * S_ * D_ * 4
                        + (size_t)bg * hg * ((size_t)S_ * S_ * 2 + (size_t)S_ * D_ * 2 + (size_t)S_ * 4)
                        + 8192;
            if (need <= ws_size) { BG = bg; HG = hg; NP = np; found = true; }
        }
    }
    size_t o_as  = alloc((size_t)B_ * NP * S_ * D_ * 4);
    size_t o_P   = alloc((size_t)BG * HG * S_ * S_ * 2);
    size_t o_att = alloc((size_t)BG * HG * S_ * D_ * 2);
    size_t o_il  = alloc((size_t)BG * HG * S_ * 4);

    __bf16* wqt = (__bf16*)(ws + o_wqt);
    __bf16* wkt = (__bf16*)(ws + o_wkt);
    __bf16* wot = (__bf16*)(ws + o_wot);
    __bf16* kvt = (__bf16*)(ws + o_kvt);
    __bf16* qb  = (__bf16*)(ws + o_qb);
    __bf16* kvb = (__bf16*)(ws + o_kvb);
    __bf16* qp  = (__bf16*)(ws + o_qp);
    __bf16* kp  = (__bf16*)(ws + o_kp);
    float*  asum = (float*)(ws + o_as);
    __bf16* Pp  = (__bf16*)(ws + o_P);
    __bf16* att = (__bf16*)(ws + o_att);
    float*  il  = (float*)(ws + o_il);

    // transposed bf16 weights + V^T, and bf16 activations
    k_tr_cvt<<<dim3(A_ / 32, D_ / 32, H_), dim3(32, 8), 0, stream>>>(Wq, wqt, D_, A_);
    k_tr_cvt<<<dim3(A_ / 32, D_ / 32, H_), dim3(32, 8), 0, stream>>>(Wk, wkt, D_, A_);
    k_tr_cvt<<<dim3(D_ / 32, D_ / 32, H_), dim3(32, 8), 0, stream>>>(Wo, wot, D_, D_);
    k_tr_cvt<<<dim3(D_ / 32, S_ / 32, B_), dim3(32, 8), 0, stream>>>(kvin, kvt, S_, D_);
    int n8 = B_ * S_ * D_ / 8;
    k_cvt<<<(n8 + 255) / 256, 256, 0, stream>>>(qin, qb, n8);
    k_cvt<<<(n8 + 255) / 256, 256, 0, stream>>>(kvin, kvb, n8);
    // projections (q pre-scaled by 1/sqrt(A))
    k_proj_gemm<<<dim3(8, 64), 256, 0, stream>>>(qb, wqt, bq, 0.125f, qp);
    k_proj_gemm<<<dim3(8, 64), 256, 0, stream>>>(kvb, wkt, bk, 1.0f, kp);
    hipMemsetAsync(asum, 0, (size_t)B_ * NP * S_ * D_ * 4, stream);

    for (int bbase = 0; bbase < B_; bbase += BG) {
        for (int hbase = 0; hbase < H_; hbase += HG) {
            k_scores<<<dim3(32, HG, BG), 256, 0, stream>>>(qp, kp, Pp, il, hbase, bbase);
            k_pv_gemm<<<dim3(D_ / 128, S_ / 128, BG * HG), 256, 0, stream>>>(Pp, kvt, il, att, bbase, HG);
            k_headsum<<<dim3(D_ / 128, S_ / 128, BG * NP), 256, 0, stream>>>(att, wot, bo, asum, hbase, HG, NP, bbase);
        }
    }
    k_ln<<<B_ * S_, 256, 0, stream>>>(qin, asum, gamma, beta, out, NP);
}